// Round 2
// baseline (316.094 us; speedup 1.0000x reference)
//
#include <hip/hip_runtime.h>

// Compact bilinear pooling, algebraically restructured:
//   out[b, (h1[c1]+h2[c2]) % D] += s1[c1]*s2[c2] * sum_hw x1[b,hw,c1]*x2[b,hw,c2]
// i.e. batched Gram GEMM (K=196) + sparse circular-conv scatter. No FFT.
//
// R2: occupancy fix. K-split x2 (grid 512->1024) + KT 14->7 shrinks LDS to
// 39.9 KB -> 4 blocks/CU (16 waves/CU vs 8). Merge atomics double (accepted).

#define NB     32
#define HW     196
#define CC     512
#define DD     8192
#define TM     128
#define TN     128
#define KT     7
#define KSPLIT 2
#define KHALF  (HW / KSPLIT)   // 98 = 14 * KT
#define NTHR   256

__global__ __launch_bounds__(NTHR, 4) void cbp_fused_kernel(
    const float* __restrict__ x1, const float* __restrict__ x2,
    const float* __restrict__ s1, const float* __restrict__ s2,
    const int*   __restrict__ h1, const int*   __restrict__ h2,
    float* __restrict__ out)
{
    __shared__ float As[KT][TM];    // 3.5 KB
    __shared__ float Bs[KT][TN];    // 3.5 KB
    __shared__ float accD[DD];      // 32 KB  (per-block circular-conv accumulator)

    const int bid = blockIdx.x;
    const int b   = bid >> 5;
    const int t1  = (bid >> 3) & 3;   // c1 tile index (4 tiles of 128)
    const int t2  = (bid >> 1) & 3;   // c2 tile index
    const int ks  = bid & 1;          // K-split half
    const int tid = threadIdx.x;

    // zero the D-bucket accumulator (synced by first barrier in K-loop)
    for (int i = tid; i < DD; i += NTHR) accD[i] = 0.0f;

    const int kbase = ks * KHALF;
    const float* X1 = x1 + ((size_t)b * HW + kbase) * CC + t1 * TM;
    const float* X2 = x2 + ((size_t)b * HW + kbase) * CC + t2 * TN;

    float acc[8][8];
    #pragma unroll
    for (int i = 0; i < 8; ++i)
        #pragma unroll
        for (int j = 0; j < 8; ++j) acc[i][j] = 0.0f;

    const int tr = tid >> 4;   // 0..15
    const int tc = tid & 15;   // 0..15

    for (int k0 = 0; k0 < KHALF; k0 += KT) {
        __syncthreads();
        // stage KT x 128 panels of X1,X2 (float4, coalesced; c-stride 1)
        for (int i = tid; i < KT * (TM / 4) * 2; i += NTHR) {
            int m   = (i >= KT * (TM / 4));
            int ii  = i - m * KT * (TM / 4);
            int row = ii / (TM / 4);
            int col = (ii % (TM / 4)) * 4;
            if (m)
                *(float4*)&Bs[row][col] = *(const float4*)&X2[(size_t)(k0 + row) * CC + col];
            else
                *(float4*)&As[row][col] = *(const float4*)&X1[(size_t)(k0 + row) * CC + col];
        }
        __syncthreads();
        #pragma unroll
        for (int kk = 0; kk < KT; ++kk) {
            float a[8], bb[8];
            #pragma unroll
            for (int i = 0; i < 8; ++i) a[i]  = As[kk][tr * 8 + i];
            #pragma unroll
            for (int j = 0; j < 8; ++j) bb[j] = Bs[kk][tc * 8 + j];
            #pragma unroll
            for (int i = 0; i < 8; ++i)
                #pragma unroll
                for (int j = 0; j < 8; ++j)
                    acc[i][j] = fmaf(a[i], bb[j], acc[i][j]);
        }
    }

    // per-thread hash/sign metadata (8 c1 rows, 8 c2 cols)
    const int c1base = t1 * TM + tr * 8;
    const int c2base = t2 * TN + tc * 8;
    int hh1[8], hh2[8];
    float ss1[8], ss2[8];
    #pragma unroll
    for (int i = 0; i < 8; ++i) { hh1[i] = h1[c1base + i]; ss1[i] = s1[c1base + i]; }
    #pragma unroll
    for (int j = 0; j < 8; ++j) { hh2[j] = h2[c2base + j]; ss2[j] = s2[c2base + j]; }

    // scatter 64 products into the D-bucket LDS accumulator
    #pragma unroll
    for (int i = 0; i < 8; ++i) {
        #pragma unroll
        for (int j = 0; j < 8; ++j) {
            int pos = (hh1[i] + hh2[j]) & (DD - 1);
            atomicAdd(&accD[pos], ss1[i] * ss2[j] * acc[i][j]);
        }
    }
    __syncthreads();

    // merge block-local buckets into the global output (device-scope atomics)
    float* ob = out + (size_t)b * DD;
    for (int i = tid; i < DD; i += NTHR)
        atomicAdd(&ob[i], accD[i]);
}

extern "C" void kernel_launch(void* const* d_in, const int* in_sizes, int n_in,
                              void* d_out, int out_size, void* d_ws, size_t ws_size,
                              hipStream_t stream) {
    const float* x1 = (const float*)d_in[0];
    const float* x2 = (const float*)d_in[1];
    const float* s1 = (const float*)d_in[2];
    const float* s2 = (const float*)d_in[3];
    const int*   h1 = (const int*)d_in[4];
    const int*   h2 = (const int*)d_in[5];
    float* out = (float*)d_out;

    // d_out is poisoned (0xAA) before every launch; we accumulate with atomics,
    // so zero it first (stream-ordered, graph-capture safe).
    hipMemsetAsync(out, 0, (size_t)out_size * sizeof(float), stream);

    dim3 grid(NB * 4 * 4 * KSPLIT);   // 32 batches x 16 Gram tiles x 2 K-halves
    dim3 block(NTHR);
    cbp_fused_kernel<<<grid, block, 0, stream>>>(x1, x2, s1, s2, h1, h2, out);
}

// Round 3
// 184.377 us; speedup vs baseline: 1.7144x; 1.7144x over previous
//
#include <hip/hip_runtime.h>

// Compact bilinear pooling, algebraically restructured:
//   out[b, (h1[c1]+h2[c2]) % D] += s1[c1]*s2[c2] * sum_hw x1[b,hw,c1]*x2[b,hw,c2]
// i.e. batched Gram GEMM (K=196) + sparse circular-conv scatter. No FFT.
//
// R3: revert KSPLIT (R2's 1024-block atomic merge caused ~15x cacheline RMW
// amplification: WRITE 16->493 MB). Keep R1's 512-block structure and fix the
// real R1 loss (VALUBusy 28%, barrier-drain on staging): double-buffered
// async global_load_lds staging, m97-style. LDS 60 KB -> 2 blocks/CU.

#define NB   32
#define HW   196
#define CC   512
#define DD   8192
#define TM   128
#define TN   128
#define KT   14
#define NIT  (HW / KT)   // 14 K-steps
#define NTHR 256

typedef const __attribute__((address_space(1))) void gvoid;
typedef __attribute__((address_space(3))) void lvoid;

__device__ __forceinline__ void gload_lds16(const float* g, float* l) {
    // async global->LDS, 16B/lane; LDS dest = wave-uniform base + lane*16
    __builtin_amdgcn_global_load_lds((gvoid*)g, (lvoid*)l, 16, 0, 0);
}

__global__ __launch_bounds__(NTHR) void cbp_fused_kernel(
    const float* __restrict__ x1, const float* __restrict__ x2,
    const float* __restrict__ s1, const float* __restrict__ s2,
    const int*   __restrict__ h1, const int*   __restrict__ h2,
    float* __restrict__ out)
{
    __shared__ float As[2][KT][TM];   // 14 KB (double-buffered)
    __shared__ float Bs[2][KT][TN];   // 14 KB
    __shared__ float accD[DD];        // 32 KB per-block circular-conv accumulator

    const int bid  = blockIdx.x;
    const int b    = bid >> 4;
    const int t1   = (bid >> 2) & 3;  // c1 tile (4 tiles of 128)
    const int t2   = bid & 3;         // c2 tile
    const int tid  = threadIdx.x;
    const int wid  = tid >> 6;        // wave 0..3
    const int lane = tid & 63;

    for (int i = tid; i < DD; i += NTHR) accD[i] = 0.0f;

    const float* X1 = x1 + (size_t)b * HW * CC + t1 * TM;
    const float* X2 = x2 + (size_t)b * HW * CC + t2 * TN;

    // --- async stage of one KT x 128 panel pair into buffer `buf` ---
    // panel = 14 rows x 512 B = 7 chunks of 1 KB; chunk c = rows 2c,2c+1.
    // LDS base is wave-uniform; HW adds lane*16. Global addr is per-lane.
    const int srow = lane >> 5;           // 0/1 within chunk
    const int scol = (lane & 31) * 4;     // float col within row
    #define STAGE(bufi, k0)                                                   \
        for (int c = wid; c < 14; c += 4) {                                   \
            int m  = (c >= 7);                                                \
            int cc = c - (m ? 7 : 0);                                         \
            const float* g = (m ? X2 : X1)                                    \
                           + (size_t)((k0) + 2 * cc + srow) * CC + scol;      \
            float* l = (m ? &Bs[bufi][0][0] : &As[bufi][0][0]) + cc * 256;    \
            gload_lds16(g, l);                                                \
        }

    STAGE(0, 0)   // prologue: stage iteration 0

    float acc[8][8];
    #pragma unroll
    for (int i = 0; i < 8; ++i)
        #pragma unroll
        for (int j = 0; j < 8; ++j) acc[i][j] = 0.0f;

    const int tr = tid >> 4;   // 0..15
    const int tc = tid & 15;   // 0..15

    for (int it = 0; it < NIT; ++it) {
        const int cur = it & 1;
        // drains vmcnt(0): buf[cur] staging complete; also fences buffer reuse
        __syncthreads();
        if (it + 1 < NIT) {
            const int nb = cur ^ 1;
            const int k0n = (it + 1) * KT;
            STAGE(nb, k0n)           // in flight across the compute phase
        }
        #pragma unroll
        for (int kk = 0; kk < KT; ++kk) {
            float a[8], bb[8];
            #pragma unroll
            for (int i = 0; i < 8; ++i) a[i]  = As[cur][kk][tr * 8 + i];
            #pragma unroll
            for (int j = 0; j < 8; ++j) bb[j] = Bs[cur][kk][tc * 8 + j];
            #pragma unroll
            for (int i = 0; i < 8; ++i)
                #pragma unroll
                for (int j = 0; j < 8; ++j)
                    acc[i][j] = fmaf(a[i], bb[j], acc[i][j]);
        }
    }

    // per-thread hash/sign metadata (8 c1 rows, 8 c2 cols)
    const int c1base = t1 * TM + tr * 8;
    const int c2base = t2 * TN + tc * 8;
    int hh1[8], hh2[8];
    float ss1[8], ss2[8];
    #pragma unroll
    for (int i = 0; i < 8; ++i) { hh1[i] = h1[c1base + i]; ss1[i] = s1[c1base + i]; }
    #pragma unroll
    for (int j = 0; j < 8; ++j) { hh2[j] = h2[c2base + j]; ss2[j] = s2[c2base + j]; }

    // scatter 64 products into the D-bucket LDS accumulator
    #pragma unroll
    for (int i = 0; i < 8; ++i) {
        #pragma unroll
        for (int j = 0; j < 8; ++j) {
            int pos = (hh1[i] + hh2[j]) & (DD - 1);
            atomicAdd(&accD[pos], ss1[i] * ss2[j] * acc[i][j]);
        }
    }
    __syncthreads();

    // merge block-local buckets into the global output.
    // 512 blocks / coalesced rows: proven benign in R1 (WRITE ~16 MB).
    float* ob = out + (size_t)b * DD;
    for (int i = tid; i < DD; i += NTHR)
        atomicAdd(&ob[i], accD[i]);
}

extern "C" void kernel_launch(void* const* d_in, const int* in_sizes, int n_in,
                              void* d_out, int out_size, void* d_ws, size_t ws_size,
                              hipStream_t stream) {
    const float* x1 = (const float*)d_in[0];
    const float* x2 = (const float*)d_in[1];
    const float* s1 = (const float*)d_in[2];
    const float* s2 = (const float*)d_in[3];
    const int*   h1 = (const int*)d_in[4];
    const int*   h2 = (const int*)d_in[5];
    float* out = (float*)d_out;

    // d_out is poisoned (0xAA) before every launch; we accumulate with atomics,
    // so zero it first (stream-ordered, graph-capture safe).
    hipMemsetAsync(out, 0, (size_t)out_size * sizeof(float), stream);

    dim3 grid(NB * 4 * 4);   // 32 batches x 4x4 tiles of the 512x512 Gram matrix
    dim3 block(NTHR);
    cbp_fused_kernel<<<grid, block, 0, stream>>>(x1, x2, s1, s2, h1, h2, out);
}

// Round 4
// 141.206 us; speedup vs baseline: 2.2385x; 1.3057x over previous
//
#include <hip/hip_runtime.h>

// Compact bilinear pooling, algebraically restructured:
//   out[b, (h1[c1]+h2[c2]) % D] += s1[c1]*s2[c2] * sum_hw x1[b,hw,c1]*x2[b,hw,c2]
// i.e. batched Gram GEMM (K=196) + sparse circular-conv scatter. No FFT.
//
// R4: Gram via bf16 MFMA (32x32x16), fragments loaded DIRECTLY from global
// (no LDS staging: per-batch panels are 0.8 MB -> L2-resident; lanes 0..31
// read 128B contiguous per (j,half) -> coalesced). LDS holds only the
// accD[8192] scatter accumulator. R1's proven 512-block grid + coalesced
// atomic merge (16 MB write). Gram FLOPs: 3.29 G -> ~1.3 us at bf16 peak;
// expect load-issue/L2-bound ~15-25 us total.
//
// MFMA layout note: A and B fragments use the SAME lane->k map, so any
// k-permutation inside one K=16 step cancels in A^T*B. C/D layout is the
// HW-verified col=lane&31, row=(reg&3)+8*(reg>>2)+4*(lane>>5).

#define NB   32
#define HW   196
#define CC   512
#define DD   8192
#define NTHR 256

typedef __attribute__((ext_vector_type(8)))  __bf16 bf8;
typedef __attribute__((ext_vector_type(16))) float  f32x16;

__global__ __launch_bounds__(NTHR) void cbp_mfma_kernel(
    const float* __restrict__ x1, const float* __restrict__ x2,
    const float* __restrict__ s1, const float* __restrict__ s2,
    const int*   __restrict__ h1, const int*   __restrict__ h2,
    float* __restrict__ out)
{
    __shared__ float accD[DD];   // 32 KB per-block circular-conv accumulator

    const int bid  = blockIdx.x;
    const int b    = bid >> 4;
    const int t1   = (bid >> 2) & 3;   // c1 tile (4 tiles of 128)
    const int t2   = bid & 3;          // c2 tile
    const int tid  = threadIdx.x;
    const int wid  = tid >> 6;         // wave 0..3
    const int lane = tid & 63;
    const int wr   = wid >> 1;         // wave row (2x2 wave grid, 64x64 each)
    const int wc   = wid & 1;
    const int lo5  = lane & 31;
    const int hi   = lane >> 5;

    for (int i = tid; i < DD; i += NTHR) accD[i] = 0.0f;
    __syncthreads();   // accD ready before any scatter atomic

    // this wave's 64x64 subtile of the 128x128 block tile
    const int c1w = t1 * 128 + wr * 64;
    const int c2w = t2 * 128 + wc * 64;

    // per-lane column pointers (k-stride = CC floats); lanes 0..31 contiguous
    const float* A0 = x1 + (size_t)b * HW * CC + (c1w + lo5);
    const float* A1 = A0 + 32;
    const float* B0 = x2 + (size_t)b * HW * CC + (c2w + lo5);
    const float* B1 = B0 + 32;

    f32x16 acc00 = {}, acc01 = {}, acc10 = {}, acc11 = {};

    // 12 full K=16 steps (k = 0..191)
    for (int ks = 0; ks < 12; ++ks) {
        const int kb = ks * 16 + hi * 8;
        bf8 a0, a1, b0v, b1v;
        #pragma unroll
        for (int j = 0; j < 8; ++j) {
            const size_t off = (size_t)(kb + j) * CC;
            a0[j]  = (__bf16)A0[off];
            a1[j]  = (__bf16)A1[off];
            b0v[j] = (__bf16)B0[off];
            b1v[j] = (__bf16)B1[off];
        }
        acc00 = __builtin_amdgcn_mfma_f32_32x32x16_bf16(a0, b0v, acc00, 0, 0, 0);
        acc01 = __builtin_amdgcn_mfma_f32_32x32x16_bf16(a0, b1v, acc01, 0, 0, 0);
        acc10 = __builtin_amdgcn_mfma_f32_32x32x16_bf16(a1, b0v, acc10, 0, 0, 0);
        acc11 = __builtin_amdgcn_mfma_f32_32x32x16_bf16(a1, b1v, acc11, 0, 0, 0);
    }
    // tail step: only k = 192..195 are valid (predicated; no OOB reads)
    {
        const int kb = 192 + hi * 8;
        bf8 a0, a1, b0v, b1v;
        #pragma unroll
        for (int j = 0; j < 8; ++j) {
            const int k = kb + j;
            const size_t off = (size_t)k * CC;
            const bool v = (k < HW);
            a0[j]  = (__bf16)(v ? A0[off] : 0.0f);
            a1[j]  = (__bf16)(v ? A1[off] : 0.0f);
            b0v[j] = (__bf16)(v ? B0[off] : 0.0f);
            b1v[j] = (__bf16)(v ? B1[off] : 0.0f);
        }
        acc00 = __builtin_amdgcn_mfma_f32_32x32x16_bf16(a0, b0v, acc00, 0, 0, 0);
        acc01 = __builtin_amdgcn_mfma_f32_32x32x16_bf16(a0, b1v, acc01, 0, 0, 0);
        acc10 = __builtin_amdgcn_mfma_f32_32x32x16_bf16(a1, b0v, acc10, 0, 0, 0);
        acc11 = __builtin_amdgcn_mfma_f32_32x32x16_bf16(a1, b1v, acc11, 0, 0, 0);
    }

    // ---- scatter into LDS circular-conv buckets ----
    // C/D layout: c2 = tile_col_base + (lane&31); c1 row from (reg, lane>>5).
    const float s2v0 = s2[c2w + lo5];
    const float s2v1 = s2[c2w + 32 + lo5];
    const int   h2v0 = h2[c2w + lo5];
    const int   h2v1 = h2[c2w + 32 + lo5];

    #pragma unroll
    for (int rt = 0; rt < 2; ++rt) {
        const f32x16 accL = rt ? acc10 : acc00;   // B-tile 0
        const f32x16 accR = rt ? acc11 : acc01;   // B-tile 1
        #pragma unroll
        for (int reg = 0; reg < 16; ++reg) {
            const int c1 = c1w + rt * 32 + (reg & 3) + 8 * (reg >> 2) + 4 * hi;
            const float sv = s1[c1];
            const int   hv = h1[c1];
            atomicAdd(&accD[(hv + h2v0) & (DD - 1)], sv * s2v0 * accL[reg]);
            atomicAdd(&accD[(hv + h2v1) & (DD - 1)], sv * s2v1 * accR[reg]);
        }
    }
    __syncthreads();

    // merge block-local buckets into global output (coalesced; proven benign
    // at 512 blocks: WRITE_SIZE = 16 MB exact in R1/R3)
    float* ob = out + (size_t)b * DD;
    for (int i = tid; i < DD; i += NTHR)
        atomicAdd(&ob[i], accD[i]);
}

extern "C" void kernel_launch(void* const* d_in, const int* in_sizes, int n_in,
                              void* d_out, int out_size, void* d_ws, size_t ws_size,
                              hipStream_t stream) {
    const float* x1 = (const float*)d_in[0];
    const float* x2 = (const float*)d_in[1];
    const float* s1 = (const float*)d_in[2];
    const float* s2 = (const float*)d_in[3];
    const int*   h1 = (const int*)d_in[4];
    const int*   h2 = (const int*)d_in[5];
    float* out = (float*)d_out;

    // d_out is poisoned (0xAA) before every launch; we accumulate with atomics,
    // so zero it first (stream-ordered, graph-capture safe).
    hipMemsetAsync(out, 0, (size_t)out_size * sizeof(float), stream);

    dim3 grid(NB * 4 * 4);   // 32 batches x 4x4 tiles of the 512x512 Gram matrix
    dim3 block(NTHR);
    cbp_mfma_kernel<<<grid, block, 0, stream>>>(x1, x2, s1, s2, h1, h2, out);
}

// Round 5
// 133.645 us; speedup vs baseline: 2.3652x; 1.0566x over previous
//
#include <hip/hip_runtime.h>

// Compact bilinear pooling, algebraically restructured:
//   out[b, (h1[c1]+h2[c2]) % D] += s1[c1]*s2[c2] * sum_hw x1[b,hw,c1]*x2[b,hw,c2]
// i.e. batched Gram GEMM (K=196) + sparse circular-conv scatter. No FFT.
//
// R5: kill the global-atomic merge (R4 floor: 4.2M device-scope RMWs ~= 25
// atomics/cyc chip-wide ~= 60 us). Blocks now plain-store their 8192-float
// bucket accumulator to a private 32KB d_ws slice; a second kernel reduces
// the 16 partials per (b,d) with streamed reads + plain stores. No atomics,
// no d_out memset. Gram GEMM identical to R4 (bf16 MFMA, direct global
// fragment loads, absmax 2.0 << 7.44).

#define NB   32
#define HW   196
#define CC   512
#define DD   8192
#define NTHR 256
#define TILES_PER_B 16   // 4x4 tiles of the 512x512 Gram

typedef __attribute__((ext_vector_type(8)))  __bf16 bf8;
typedef __attribute__((ext_vector_type(16))) float  f32x16;

__global__ __launch_bounds__(NTHR) void cbp_mfma_kernel(
    const float* __restrict__ x1, const float* __restrict__ x2,
    const float* __restrict__ s1, const float* __restrict__ s2,
    const int*   __restrict__ h1, const int*   __restrict__ h2,
    float* __restrict__ ws, float* __restrict__ out, int use_ws)
{
    __shared__ float accD[DD];   // 32 KB per-block circular-conv accumulator

    const int bid  = blockIdx.x;
    const int b    = bid >> 4;
    const int t1   = (bid >> 2) & 3;   // c1 tile (4 tiles of 128)
    const int t2   = bid & 3;          // c2 tile
    const int tid  = threadIdx.x;
    const int wid  = tid >> 6;         // wave 0..3
    const int lane = tid & 63;
    const int wr   = wid >> 1;         // wave row (2x2 wave grid, 64x64 each)
    const int wc   = wid & 1;
    const int lo5  = lane & 31;
    const int hi   = lane >> 5;

    for (int i = tid; i < DD; i += NTHR) accD[i] = 0.0f;
    __syncthreads();   // accD ready before any scatter atomic

    // this wave's 64x64 subtile of the 128x128 block tile
    const int c1w = t1 * 128 + wr * 64;
    const int c2w = t2 * 128 + wc * 64;

    // per-lane column pointers (k-stride = CC floats); lanes 0..31 contiguous
    const float* A0 = x1 + (size_t)b * HW * CC + (c1w + lo5);
    const float* A1 = A0 + 32;
    const float* B0 = x2 + (size_t)b * HW * CC + (c2w + lo5);
    const float* B1 = B0 + 32;

    f32x16 acc00 = {}, acc01 = {}, acc10 = {}, acc11 = {};

    // 12 full K=16 steps (k = 0..191)
    for (int ks = 0; ks < 12; ++ks) {
        const int kb = ks * 16 + hi * 8;
        bf8 a0, a1, b0v, b1v;
        #pragma unroll
        for (int j = 0; j < 8; ++j) {
            const size_t off = (size_t)(kb + j) * CC;
            a0[j]  = (__bf16)A0[off];
            a1[j]  = (__bf16)A1[off];
            b0v[j] = (__bf16)B0[off];
            b1v[j] = (__bf16)B1[off];
        }
        acc00 = __builtin_amdgcn_mfma_f32_32x32x16_bf16(a0, b0v, acc00, 0, 0, 0);
        acc01 = __builtin_amdgcn_mfma_f32_32x32x16_bf16(a0, b1v, acc01, 0, 0, 0);
        acc10 = __builtin_amdgcn_mfma_f32_32x32x16_bf16(a1, b0v, acc10, 0, 0, 0);
        acc11 = __builtin_amdgcn_mfma_f32_32x32x16_bf16(a1, b1v, acc11, 0, 0, 0);
    }
    // tail step: only k = 192..195 are valid (predicated; no OOB reads)
    {
        const int kb = 192 + hi * 8;
        bf8 a0, a1, b0v, b1v;
        #pragma unroll
        for (int j = 0; j < 8; ++j) {
            const int k = kb + j;
            const size_t off = (size_t)k * CC;
            const bool v = (k < HW);
            a0[j]  = (__bf16)(v ? A0[off] : 0.0f);
            a1[j]  = (__bf16)(v ? A1[off] : 0.0f);
            b0v[j] = (__bf16)(v ? B0[off] : 0.0f);
            b1v[j] = (__bf16)(v ? B1[off] : 0.0f);
        }
        acc00 = __builtin_amdgcn_mfma_f32_32x32x16_bf16(a0, b0v, acc00, 0, 0, 0);
        acc01 = __builtin_amdgcn_mfma_f32_32x32x16_bf16(a0, b1v, acc01, 0, 0, 0);
        acc10 = __builtin_amdgcn_mfma_f32_32x32x16_bf16(a1, b0v, acc10, 0, 0, 0);
        acc11 = __builtin_amdgcn_mfma_f32_32x32x16_bf16(a1, b1v, acc11, 0, 0, 0);
    }

    // ---- scatter into LDS circular-conv buckets ----
    // C/D layout: c2 = tile_col_base + (lane&31); c1 row from (reg, lane>>5).
    const float s2v0 = s2[c2w + lo5];
    const float s2v1 = s2[c2w + 32 + lo5];
    const int   h2v0 = h2[c2w + lo5];
    const int   h2v1 = h2[c2w + 32 + lo5];

    #pragma unroll
    for (int rt = 0; rt < 2; ++rt) {
        const f32x16 accL = rt ? acc10 : acc00;   // B-tile 0
        const f32x16 accR = rt ? acc11 : acc01;   // B-tile 1
        #pragma unroll
        for (int reg = 0; reg < 16; ++reg) {
            const int c1 = c1w + rt * 32 + (reg & 3) + 8 * (reg >> 2) + 4 * hi;
            const float sv = s1[c1];
            const int   hv = h1[c1];
            atomicAdd(&accD[(hv + h2v0) & (DD - 1)], sv * s2v0 * accL[reg]);
            atomicAdd(&accD[(hv + h2v1) & (DD - 1)], sv * s2v1 * accR[reg]);
        }
    }
    __syncthreads();

    if (use_ws) {
        // plain coalesced float4 stores to this block's private partial slice
        float4* dst = (float4*)(ws + (size_t)bid * DD);
        const float4* src = (const float4*)accD;
        #pragma unroll
        for (int i = 0; i < DD / 4 / NTHR; ++i)
            dst[tid + i * NTHR] = src[tid + i * NTHR];
    } else {
        // fallback (ws too small): device atomics, R4 behavior
        float* ob = out + (size_t)b * DD;
        for (int i = tid; i < DD; i += NTHR)
            atomicAdd(&ob[i], accD[i]);
    }
}

// out[b][d] = sum_{t=0..15} ws[(b*16+t)][d]; 256 blocks x 256 thr, float4/thr
__global__ __launch_bounds__(NTHR) void cbp_reduce_kernel(
    const float* __restrict__ ws, float* __restrict__ out)
{
    const int b   = blockIdx.x >> 3;           // 8 blocks per batch
    const int d0  = (blockIdx.x & 7) * 1024 + threadIdx.x * 4;
    const float* base = ws + (size_t)b * TILES_PER_B * DD + d0;
    float4 sum = {0.f, 0.f, 0.f, 0.f};
    #pragma unroll
    for (int t = 0; t < TILES_PER_B; ++t) {
        float4 v = *(const float4*)(base + (size_t)t * DD);
        sum.x += v.x; sum.y += v.y; sum.z += v.z; sum.w += v.w;
    }
    *(float4*)(out + (size_t)b * DD + d0) = sum;
}

extern "C" void kernel_launch(void* const* d_in, const int* in_sizes, int n_in,
                              void* d_out, int out_size, void* d_ws, size_t ws_size,
                              hipStream_t stream) {
    const float* x1 = (const float*)d_in[0];
    const float* x2 = (const float*)d_in[1];
    const float* s1 = (const float*)d_in[2];
    const float* s2 = (const float*)d_in[3];
    const int*   h1 = (const int*)d_in[4];
    const int*   h2 = (const int*)d_in[5];
    float* out = (float*)d_out;
    float* ws  = (float*)d_ws;

    const size_t need = (size_t)NB * TILES_PER_B * DD * sizeof(float);  // 16.8 MB
    const int use_ws = (ws_size >= need) ? 1 : 0;

    if (!use_ws) {
        // atomic fallback needs a zeroed output (d_out is poisoned 0xAA)
        hipMemsetAsync(out, 0, (size_t)out_size * sizeof(float), stream);
    }

    dim3 grid(NB * TILES_PER_B);   // 512 blocks
    dim3 block(NTHR);
    cbp_mfma_kernel<<<grid, block, 0, stream>>>(x1, x2, s1, s2, h1, h2, ws, out, use_ws);

    if (use_ws) {
        dim3 rgrid(NB * 8);        // 256 blocks, each reduces 1024 buckets
        cbp_reduce_kernel<<<rgrid, block, 0, stream>>>(ws, out);
    }
}